// Round 14
// baseline (169.062 us; speedup 1.0000x reference)
//
#include <hip/hip_runtime.h>
#include <math.h>

#define Dk 1024
#define Hk 256
#define Lk 8192
#define Bk 8
#define MTOT (Bk*Lk)   // 65536 rows

typedef _Float16 f16;
typedef __attribute__((ext_vector_type(8))) _Float16 f16x8;
typedef __attribute__((ext_vector_type(4))) _Float16 f16x4;
typedef __attribute__((ext_vector_type(16))) float f32x16;
typedef unsigned long long u64;

#define BSTEP 16384          // B f16 elems per K32 step (32KB)
#define AR 20                // A row stride in f16 (40B): 2-way banks
#define APL (128*AR)         // A plane (kc) stride = 2560
#define ABUF (4*APL)         // [sp2][kc2][row128][AR] = 10240 f16 per buffer

// async global->LDS, 16B per lane (lane-linear LDS dest required)
#define GLD_LDS16(g, l)                                                        \
  __builtin_amdgcn_global_load_lds(                                            \
      (const __attribute__((address_space(1))) unsigned int*)(g),              \
      (__attribute__((address_space(3))) unsigned int*)(l), 16, 0, 0)

// ---------------- prep_split: W1 -> gamma-folded fp16 2-way split (hi, lo*2048)
// in 32x32x16-fragment DMA order + partials for S,T.
// d = s*32 + kc*16 + kh*8 + kk ; h = cb*32 + c
// W1F[s][sp2][kc2][cb8][ (kh*32+c)*8 + kk ]
__global__ __launch_bounds__(1024) void prep_split(
    const float* __restrict__ W1, const float* __restrict__ gamma,
    const float* __restrict__ beta, f16* __restrict__ W1F,
    float* __restrict__ Spart, float* __restrict__ Tpart) {
  __shared__ float ps[1024], pt[1024];
  const int b = blockIdx.x, t = threadIdx.x;
  float sa = 0.f, ta = 0.f;
  #pragma unroll
  for (int j = 0; j < 4; ++j) {
    int idx = j * 65536 + b * 1024 + t;
    int d = idx >> 8, h = idx & 255;
    float w = W1[idx];
    float g = gamma[d];
    sa = fmaf(g, w, sa);
    ta = fmaf(beta[d], w, ta);
    float wg = g * w;                       // gamma folded into W1
    f16 whi = (f16)wg;
    f16 wlp = (f16)((wg - (float)whi) * 2048.f);   // scaled lo: fp16-normal
    int s = d >> 5, kc = (d >> 4) & 1, kh = (d >> 3) & 1, kk = d & 7;
    int cb = h >> 5, c = h & 31;
    size_t base = (size_t)s * BSTEP + ((size_t)kc * 8 + cb) * 512
                + (kh * 32 + c) * 8 + kk;
    W1F[base] = whi;
    W1F[base + 8192] = wlp;                 // sp stride = 2*8*512
  }
  ps[t] = sa; pt[t] = ta;
  __syncthreads();
  if (t < 256) {
    Spart[b * 256 + t] = ps[t] + ps[t + 256] + ps[t + 512] + ps[t + 768];
    Tpart[b * 256 + t] = pt[t] + pt[t + 256] + pt[t + 512] + pt[t + 768];
  }
}

__global__ __launch_bounds__(256) void prep_combine(
    const float* __restrict__ Spart, const float* __restrict__ Tpart,
    const float* __restrict__ b1, float* __restrict__ S, float* __restrict__ Tb) {
  int j = threadIdx.x;
  float s = 0.f, t = 0.f;
  for (int b = 0; b < 64; ++b) { s += Spart[b * 256 + j]; t += Tpart[b * 256 + j]; }
  S[j] = s;
  Tb[j] = t + b1[j];
}

// 3-product split-fp16 triple (32x32x16): accA += ah*wh; accB += ah*wl + ax*wh
#define MM3(aA, aB, ah, ax, wh, wl)                                            \
  aA = __builtin_amdgcn_mfma_f32_32x32x16_f16(ah, wh, aA, 0, 0, 0);            \
  aB = __builtin_amdgcn_mfma_f32_32x32x16_f16(ah, wl, aB, 0, 0, 0);            \
  aB = __builtin_amdgcn_mfma_f32_32x32x16_f16(ax, wh, aB, 0, 0, 0);

// ---------------- scores: fused LN + Linear(1024->256) + GELU + Linear(256->1)
// R13 structure + T4 counted-vmcnt barriers + TRIPLE-buffered B DMA:
// DMA issued at step s targets buffer (s+2)%3 -> two full steps of slack, and
// the per-step barrier no longer drains vmcnt(0) (the m97 barrier-drain stall,
// 27% MfmaUtil in R13). Every step issues EXACTLY 3 VMEM ops (2 B-DMA + 1 A
// prefetch; tail steps issue safe dummies) so "s_waitcnt vmcnt(3)" at the
// barrier leaves only the two younger DMAs + prefetch in flight -- DMA(s+1)
// is guaranteed landed when step s+1 reads it (m201-verified protocol).
__global__ __launch_bounds__(1024) void scores_mfma(
    const float* __restrict__ F, const f16* __restrict__ W1F,
    const float* __restrict__ S, const float* __restrict__ Tb,
    const float* __restrict__ W2, const float* __restrict__ b2,
    float* __restrict__ scores_out) {
  __shared__ __align__(16) f16 As[2][ABUF];     // 40KB
  __shared__ __align__(16) f16 Bs[3][BSTEP];    // 96KB (triple buffer)
  __shared__ float smu[128], srs[128];
  __shared__ float sred[128][4];

  const int tid = threadIdx.x;
  const int RM = blockIdx.x * 128;
  const int w = tid >> 6, lane = tid & 63;
  const int rg = w & 3;          // row group: rows rg*32..+31
  const int cg = w >> 2;         // col group: cols cg*64..+63
  const int c31 = lane & 31, kh = lane >> 5;

  // A staging: thread -> (row 0..127, 4 consecutive k of the 32-wide step)
  const int arow = tid >> 3, kq = tid & 7;      // k = kq*4..kq*4+3
  const int akc = kq >> 2, akoff = (kq & 3) * 4;
  const int aw0 = (akc * 128 + arow) * AR + akoff;   // sp0 write; sp1 at +2*APL
  const float* Aptr = F + (size_t)(RM + arow) * Dk + kq * 4;

  // A frag read base (sp0,kc0): two b64 at +0,+4
  const int ar0 = (rg * 32 + c31) * AR + kh * 8;
  // B frag read base (sp0,kc0,nf0): lane-linear 16B
  const int br0 = (cg * 2) * 512 + lane * 8;

  f32x16 accA[2], accB[2];
  accA[0] = (f32x16)(0.f); accB[0] = (f32x16)(0.f);
  accA[1] = (f32x16)(0.f); accB[1] = (f32x16)(0.f);

  float rsum = 0.f, rsq = 0.f;

  // stats + fp16 2-way split of 4 raw elems -> two b64 LDS writes
#define SPLIT4(buf, fv)                                                        \
  {                                                                            \
    f16x4 vhi, vlo;                                                            \
    _Pragma("unroll")                                                          \
    for (int e = 0; e < 4; ++e) {                                              \
      float x = (e == 0) ? fv.x : (e == 1) ? fv.y : (e == 2) ? fv.z : fv.w;    \
      rsum += x; rsq = fmaf(x, x, rsq);                                        \
      f16 hi = (f16)x;                                                         \
      vhi[e] = hi;                                                             \
      vlo[e] = (f16)((x - (float)hi) * 2048.f);                                \
    }                                                                          \
    *reinterpret_cast<f16x4*>(&As[buf][aw0])           = vhi;                  \
    *reinterpret_cast<f16x4*>(&As[buf][aw0 + 2 * APL]) = vlo;                  \
  }

  // counted-vmcnt barrier: own DMA(step+1) drained, ds ops drained, sync.
#define STEP_BARRIER()                                                         \
  asm volatile("s_waitcnt vmcnt(3) lgkmcnt(0)" ::: "memory");                  \
  __builtin_amdgcn_s_barrier();                                                \
  asm volatile("" ::: "memory");

  // prologue: DMA B(0)->Bs[0], B(1)->Bs[1]; split A(0); prefetch raw A(1)
  GLD_LDS16(W1F + (size_t)tid * 8, &Bs[0][tid * 8]);
  GLD_LDS16(W1F + (size_t)(1024 + tid) * 8, &Bs[0][8192 + tid * 8]);
  GLD_LDS16(W1F + BSTEP + (size_t)tid * 8, &Bs[1][tid * 8]);
  GLD_LDS16(W1F + BSTEP + (size_t)(1024 + tid) * 8, &Bs[1][8192 + tid * 8]);
  float4 av = *reinterpret_cast<const float4*>(Aptr);
  SPLIT4(0, av)
  av = *reinterpret_cast<const float4*>(Aptr + 32);
  // in flight: DMA(0) x2 (wait), DMA(1) x2 + av x1 (3 younger) -> vmcnt(3)
  asm volatile("s_waitcnt vmcnt(3) lgkmcnt(0)" ::: "memory");
  __builtin_amdgcn_s_barrier();
  asm volatile("" ::: "memory");

  for (int s = 0; s < 32; ++s) {
    const int cur = s & 1;
    const int bcur = s % 3, bnxt = (s + 2) % 3;
    // ---- issue DMA(s+2) (2 VMEM ops; dummy-safe source past the end)
    {
      const f16* bsrc = W1F + (size_t)((s + 2) < 32 ? (s + 2) : 0) * BSTEP;
      GLD_LDS16(bsrc + (size_t)tid * 8, &Bs[bnxt][tid * 8]);
      GLD_LDS16(bsrc + (size_t)(1024 + tid) * 8, &Bs[bnxt][8192 + tid * 8]);
    }
    // ---- split tile s+1 into As[cur^1] (VALU + ds_writes)
    if (s < 31) SPLIT4(cur ^ 1, av)
    // ---- A raw prefetch for step s+2 (1 VMEM op; dummy-safe at tail)
    av = *reinterpret_cast<const float4*>(s < 30 ? Aptr + (s + 2) * 32 : Aptr);
    // ---- MFMA phase: all operands from LDS (buffers staged >=2 steps ago)
    #pragma unroll
    for (int kc = 0; kc < 2; ++kc) {
      const f16* ab = &As[cur][kc * APL + ar0];
      f16x4 h0 = *reinterpret_cast<const f16x4*>(ab);
      f16x4 h1 = *reinterpret_cast<const f16x4*>(ab + 4);
      f16x4 x0 = *reinterpret_cast<const f16x4*>(ab + 2 * APL);
      f16x4 x1 = *reinterpret_cast<const f16x4*>(ab + 2 * APL + 4);
      f16x8 ahi = __builtin_shufflevector(h0, h1, 0, 1, 2, 3, 4, 5, 6, 7);
      f16x8 axl = __builtin_shufflevector(x0, x1, 0, 1, 2, 3, 4, 5, 6, 7);
      #pragma unroll
      for (int nf = 0; nf < 2; ++nf) {
        const f16* bb = &Bs[bcur][kc * 4096 + nf * 512 + br0];
        f16x8 wh = *reinterpret_cast<const f16x8*>(bb);
        f16x8 wl = *reinterpret_cast<const f16x8*>(bb + 8192);
        MM3(accA[nf], accB[nf], ahi, axl, wh, wl)
      }
    }
    // ---- counted barrier: drains DMA(s+1) (for next step) but NOT DMA(s+2)
    STEP_BARRIER()
  }

  __syncthreads();   // full drain (incl. tail dummy DMAs) before epilogue

  // finish stats: row owned by 8 threads (kq 0..7)
  rsum += __shfl_xor(rsum, 1); rsum += __shfl_xor(rsum, 2); rsum += __shfl_xor(rsum, 4);
  rsq  += __shfl_xor(rsq, 1);  rsq  += __shfl_xor(rsq, 2);  rsq  += __shfl_xor(rsq, 4);
  if ((tid & 7) == 0) {
    float mu  = rsum * (1.f / 1024.f);
    float var = rsq * (1.f / 1024.f) - mu * mu;
    smu[arow] = mu;
    srs[arow] = rsqrtf(var + 1e-5f);
  }
  __syncthreads();

  // epilogue: 32x32 C/D layout: col = lane&31, row = (reg&3)+8*(reg>>2)+4*(lane>>5)
  float s2[2], tb2[2], w2v[2];
  #pragma unroll
  for (int nf = 0; nf < 2; ++nf) {
    int col = cg * 64 + nf * 32 + c31;
    s2[nf] = S[col]; tb2[nf] = Tb[col]; w2v[nf] = W2[col];
  }
  #pragma unroll
  for (int reg = 0; reg < 16; ++reg) {
    const int row = rg * 32 + (reg & 3) + 8 * (reg >> 2) + 4 * kh;
    float mu = smu[row], rs = srs[row];
    float part = 0.f;
    #pragma unroll
    for (int nf = 0; nf < 2; ++nf) {
      float val = accA[nf][reg] + accB[nf][reg] * (1.f / 2048.f);
      float hpre = rs * val - rs * mu * s2[nf] + tb2[nf];
      float g = 0.5f * hpre * (1.f + erff(hpre * 0.70710678118654752f));
      part = fmaf(g, w2v[nf], part);
    }
    part += __shfl_xor(part, 1); part += __shfl_xor(part, 2);
    part += __shfl_xor(part, 4); part += __shfl_xor(part, 8);
    part += __shfl_xor(part, 16);
    if (c31 == 0) sred[row][cg] = part;
  }
  __syncthreads();
  if (tid < 128) {
    float sc = b2[0] + sred[tid][0] + sred[tid][1] + sred[tid][2] + sred[tid][3];
    scores_out[RM + tid] = sc;
  }
}

// ---------------- topk stage 1: 64 blocks, each sorts a 1024-score chunk
// (keys ascending = scores descending, idx-asc ties) and keeps top 512.
__global__ __launch_bounds__(512) void topk_stage1(
    const float* __restrict__ scores, u64* __restrict__ kout) {
  __shared__ u64 keys[1024];
  const int blk = blockIdx.x;
  const int batch = blk >> 3, chunk = blk & 7;
  const int t = threadIdx.x;
  #pragma unroll
  for (int j = 0; j < 2; ++j) {
    int i = t + j * 512;
    int gi = chunk * 1024 + i;                 // within-batch index
    unsigned u = __float_as_uint(scores[(size_t)batch * Lk + gi]);
    unsigned mono = (u & 0x80000000u) ? ~u : (u | 0x80000000u);
    keys[i] = ((u64)(~mono) << 32) | (unsigned)gi;
  }
  __syncthreads();
  for (int size = 2; size <= 1024; size <<= 1) {
    for (int stride = size >> 1; stride > 0; stride >>= 1) {
      int lo = ((t & ~(stride - 1)) << 1) | (t & (stride - 1));
      int hi = lo + stride;
      bool up = ((lo & size) == 0);
      u64 a = keys[lo], c = keys[hi];
      if ((a > c) == up) { keys[lo] = c; keys[hi] = a; }
      __syncthreads();
    }
  }
  kout[(size_t)blk * 512 + t] = keys[t];       // smallest 512 keys = top scores
}

// ---------------- topk stage 2: 8 blocks, tree-merge 8 sorted 512-lists.
__global__ __launch_bounds__(512) void topk_stage2(
    const u64* __restrict__ kin, int k,
    float* __restrict__ idx_f, int* __restrict__ idx_i) {
  __shared__ u64 kk[4096];
  __shared__ u64 tmp[2048];
  const int b = blockIdx.x, t = threadIdx.x;
  #pragma unroll
  for (int j = 0; j < 8; ++j) kk[t + j * 512] = kin[(size_t)b * 4096 + t + j * 512];
  __syncthreads();
  // level 0: kk (8 runs) -> tmp (4 runs)
  #pragma unroll
  for (int j = 0; j < 4; ++j) {
    u64 a = kk[j * 1024 + t];
    u64 c = kk[j * 1024 + 512 + (511 - t)];
    tmp[j * 512 + t] = a < c ? a : c;
  }
  __syncthreads();
  for (int stride = 256; stride > 0; stride >>= 1) {
    #pragma unroll
    for (int w = 0; w < 2; ++w) {
      int p = t + w * 512;                     // 1024 disjoint pairs
      int r = p >> 8, q = p & 255;
      int lo = r * 512 + (((q & ~(stride - 1)) << 1) | (q & (stride - 1)));
      u64 a = tmp[lo], c = tmp[lo + stride];
      if (a > c) { tmp[lo] = c; tmp[lo + stride] = a; }
    }
    __syncthreads();
  }
  // level 1: tmp (4 runs) -> kk (2 runs)
  #pragma unroll
  for (int j = 0; j < 2; ++j) {
    u64 a = tmp[j * 1024 + t];
    u64 c = tmp[j * 1024 + 512 + (511 - t)];
    kk[j * 512 + t] = a < c ? a : c;
  }
  __syncthreads();
  for (int stride = 256; stride > 0; stride >>= 1) {
    int r = t >> 8, q = t & 255;               // 512 pairs over 2 runs
    int lo = r * 512 + (((q & ~(stride - 1)) << 1) | (q & (stride - 1)));
    u64 a = kk[lo], c = kk[lo + stride];
    if (a > c) { kk[lo] = c; kk[lo + stride] = a; }
    __syncthreads();
  }
  // level 2: kk (2 runs) -> tmp[0..512)
  {
    u64 a = kk[t];
    u64 c = kk[512 + (511 - t)];
    tmp[t] = a < c ? a : c;
  }
  __syncthreads();
  for (int stride = 256; stride > 0; stride >>= 1) {
    if (t < 256) {
      int lo = ((t & ~(stride - 1)) << 1) | (t & (stride - 1));
      u64 a = tmp[lo], c = tmp[lo + stride];
      if (a > c) { tmp[lo] = c; tmp[lo + stride] = a; }
    }
    __syncthreads();
  }
  if (t < k) {
    int id = (int)(tmp[t] & 0xFFFFFFFFu);
    idx_f[(size_t)b * k + t] = (float)id;
    idx_i[(size_t)b * k + t] = id;
  }
}

// ---------------- gather: one block per selected row, 4 KB float4 copy
__global__ __launch_bounds__(256) void gather_kernel(
    const float* __restrict__ F, const int* __restrict__ idx,
    float* __restrict__ out, int k) {
  int row = blockIdx.x;          // 0 .. 8*k-1
  int b = row / k;
  int id = idx[row];
  const float4* src = reinterpret_cast<const float4*>(F + ((size_t)b * Lk + id) * Dk);
  float4* dst = reinterpret_cast<float4*>(out + (size_t)row * Dk);
  dst[threadIdx.x] = src[threadIdx.x];
}

extern "C" void kernel_launch(void* const* d_in, const int* in_sizes, int n_in,
                              void* d_out, int out_size, void* d_ws, size_t ws_size,
                              hipStream_t stream) {
  const float* F     = (const float*)d_in[0];
  const float* gamma = (const float*)d_in[1];
  const float* beta  = (const float*)d_in[2];
  const float* W1    = (const float*)d_in[3];
  const float* b1    = (const float*)d_in[4];
  const float* W2    = (const float*)d_in[5];
  const float* b2    = (const float*)d_in[6];
  // k lives on device; derive on host from out_size = 8*k*1024 + 8*8192 + 8*k
  int k = (out_size - Bk * Lk) / (Bk * Dk + Bk);   // = 512

  float* out_sel = (float*)d_out;                       // [8, k, 1024]
  float* out_sc  = out_sel + (size_t)Bk * k * Dk;       // [8, 8192]
  float* out_idx = out_sc + (size_t)Bk * Lk;            // [8, k] as float

  // ws: W1F f16[524288] (1MB) | kout u64[32768] (256KB) | Spart f32[16384] |
  //     Tpart f32[16384] | S f32[256] | Tb f32[256] | idxi i32[8*k]
  f16*   W1F   = (f16*)d_ws;
  u64*   kout  = (u64*)((char*)d_ws + (1 << 20));
  float* Spart = (float*)((char*)kout + 262144);
  float* Tpart = Spart + 16384;
  float* Sp    = Tpart + 16384;
  float* Tbp   = Sp + Hk;
  int*   idxi  = (int*)(Tbp + Hk);

  hipLaunchKernelGGL(prep_split,   dim3(64),         dim3(1024), 0, stream,
                     W1, gamma, beta, W1F, Spart, Tpart);
  hipLaunchKernelGGL(prep_combine, dim3(1),          dim3(Hk),   0, stream,
                     Spart, Tpart, b1, Sp, Tbp);
  hipLaunchKernelGGL(scores_mfma,  dim3(MTOT / 128), dim3(1024), 0, stream,
                     F, W1F, Sp, Tbp, W2, b2, out_sc);
  hipLaunchKernelGGL(topk_stage1,  dim3(64),         dim3(512),  0, stream,
                     out_sc, kout);
  hipLaunchKernelGGL(topk_stage2,  dim3(Bk),         dim3(512),  0, stream,
                     kout, k, out_idx, idxi);
  hipLaunchKernelGGL(gather_kernel, dim3(Bk * k),    dim3(256),  0, stream,
                     F, idxi, out_sel, k);
}

// Round 15
// 164.225 us; speedup vs baseline: 1.0295x; 1.0295x over previous
//
#include <hip/hip_runtime.h>
#include <math.h>

#define Dk 1024
#define Hk 256
#define Lk 8192
#define Bk 8
#define MTOT (Bk*Lk)   // 65536 rows

typedef _Float16 f16;
typedef __attribute__((ext_vector_type(8))) _Float16 f16x8;
typedef __attribute__((ext_vector_type(4))) _Float16 f16x4;
typedef __attribute__((ext_vector_type(16))) float f32x16;
typedef unsigned long long u64;

#define BSTEP 16384          // B f16 elems per K32 step (32KB)
#define AR 20                // A row stride in f16 (40B): 2-way banks
#define APL (128*AR)         // A plane (kc) stride = 2560
#define ABUF (4*APL)         // [sp2][kc2][row128][AR] = 10240 f16 per buffer

// async global->LDS, 16B per lane (lane-linear LDS dest required)
#define GLD_LDS16(g, l)                                                        \
  __builtin_amdgcn_global_load_lds(                                            \
      (const __attribute__((address_space(1))) unsigned int*)(g),              \
      (__attribute__((address_space(3))) unsigned int*)(l), 16, 0, 0)

// ---------------- prep_split: W1 -> gamma-folded fp16 2-way split (hi, lo*2048)
// in 32x32x16-fragment DMA order + partials for S,T.
// d = s*32 + kc*16 + kh*8 + kk ; h = cb*32 + c
// W1F[s][sp2][kc2][cb8][ (kh*32+c)*8 + kk ]
__global__ __launch_bounds__(1024) void prep_split(
    const float* __restrict__ W1, const float* __restrict__ gamma,
    const float* __restrict__ beta, f16* __restrict__ W1F,
    float* __restrict__ Spart, float* __restrict__ Tpart) {
  __shared__ float ps[1024], pt[1024];
  const int b = blockIdx.x, t = threadIdx.x;
  float sa = 0.f, ta = 0.f;
  #pragma unroll
  for (int j = 0; j < 4; ++j) {
    int idx = j * 65536 + b * 1024 + t;
    int d = idx >> 8, h = idx & 255;
    float w = W1[idx];
    float g = gamma[d];
    sa = fmaf(g, w, sa);
    ta = fmaf(beta[d], w, ta);
    float wg = g * w;                       // gamma folded into W1
    f16 whi = (f16)wg;
    f16 wlp = (f16)((wg - (float)whi) * 2048.f);   // scaled lo: fp16-normal
    int s = d >> 5, kc = (d >> 4) & 1, kh = (d >> 3) & 1, kk = d & 7;
    int cb = h >> 5, c = h & 31;
    size_t base = (size_t)s * BSTEP + ((size_t)kc * 8 + cb) * 512
                + (kh * 32 + c) * 8 + kk;
    W1F[base] = whi;
    W1F[base + 8192] = wlp;                 // sp stride = 2*8*512
  }
  ps[t] = sa; pt[t] = ta;
  __syncthreads();
  if (t < 256) {
    Spart[b * 256 + t] = ps[t] + ps[t + 256] + ps[t + 512] + ps[t + 768];
    Tpart[b * 256 + t] = pt[t] + pt[t + 256] + pt[t + 512] + pt[t + 768];
  }
}

__global__ __launch_bounds__(256) void prep_combine(
    const float* __restrict__ Spart, const float* __restrict__ Tpart,
    const float* __restrict__ b1, float* __restrict__ S, float* __restrict__ Tb) {
  int j = threadIdx.x;
  float s = 0.f, t = 0.f;
  for (int b = 0; b < 64; ++b) { s += Spart[b * 256 + j]; t += Tpart[b * 256 + j]; }
  S[j] = s;
  Tb[j] = t + b1[j];
}

// 3-product split-fp16 triple (32x32x16): accA += ah*wh; accB += ah*wl + ax*wh
#define MM3(aA, aB, ah, ax, wh, wl)                                            \
  aA = __builtin_amdgcn_mfma_f32_32x32x16_f16(ah, wh, aA, 0, 0, 0);            \
  aB = __builtin_amdgcn_mfma_f32_32x32x16_f16(ah, wl, aB, 0, 0, 0);            \
  aB = __builtin_amdgcn_mfma_f32_32x32x16_f16(ax, wh, aB, 0, 0, 0);

// ---------------- scores: fused LN + Linear(1024->256) + GELU + Linear(256->1)
// R14 protocol (triple-buffered B DMA, counted vmcnt) + m201-style PHASE SPLIT:
// each K32 step = 2 phases (kc0 | kc1), each phase =
//   {ds_read frags; issue stage op; s_barrier; lgkmcnt(0); sched_barrier;
//    setprio(1); 6 MFMA; setprio(0); s_barrier}
// Phase-split creates wave role diversity (m196 +28-41%) and makes setprio
// effective (m218b: +21-25% WITH phases, 0% lockstep = our R10 null).
// MFMA order per accumulator unchanged => scores bit-identical to R13/R14.
__global__ __launch_bounds__(1024) void scores_mfma(
    const float* __restrict__ F, const f16* __restrict__ W1F,
    const float* __restrict__ S, const float* __restrict__ Tb,
    const float* __restrict__ W2, const float* __restrict__ b2,
    float* __restrict__ scores_out) {
  __shared__ __align__(16) f16 As[2][ABUF];     // 40KB
  __shared__ __align__(16) f16 Bs[3][BSTEP];    // 96KB (triple buffer)
  __shared__ float smu[128], srs[128];
  __shared__ float sred[128][4];

  const int tid = threadIdx.x;
  const int RM = blockIdx.x * 128;
  const int w = tid >> 6, lane = tid & 63;
  const int rg = w & 3;          // row group: rows rg*32..+31
  const int cg = w >> 2;         // col group: cols cg*64..+63
  const int c31 = lane & 31, kh = lane >> 5;

  // A staging: thread -> (row 0..127, 4 consecutive k of the 32-wide step)
  const int arow = tid >> 3, kq = tid & 7;      // k = kq*4..kq*4+3
  const int akc = kq >> 2, akoff = (kq & 3) * 4;
  const int aw0 = (akc * 128 + arow) * AR + akoff;   // sp0 write; sp1 at +2*APL
  const float* Aptr = F + (size_t)(RM + arow) * Dk + kq * 4;

  // A frag read base (sp0,kc0): two b64 at +0,+4
  const int ar0 = (rg * 32 + c31) * AR + kh * 8;
  // B frag read base (sp0,kc0,nf0): lane-linear 16B
  const int br0 = (cg * 2) * 512 + lane * 8;

  f32x16 accA[2], accB[2];
  accA[0] = (f32x16)(0.f); accB[0] = (f32x16)(0.f);
  accA[1] = (f32x16)(0.f); accB[1] = (f32x16)(0.f);

  float rsum = 0.f, rsq = 0.f;

  // stats + fp16 2-way split of 4 raw elems -> two b64 LDS writes
#define SPLIT4(buf, fv)                                                        \
  {                                                                            \
    f16x4 vhi, vlo;                                                            \
    _Pragma("unroll")                                                          \
    for (int e = 0; e < 4; ++e) {                                              \
      float x = (e == 0) ? fv.x : (e == 1) ? fv.y : (e == 2) ? fv.z : fv.w;    \
      rsum += x; rsq = fmaf(x, x, rsq);                                        \
      f16 hi = (f16)x;                                                         \
      vhi[e] = hi;                                                             \
      vlo[e] = (f16)((x - (float)hi) * 2048.f);                                \
    }                                                                          \
    *reinterpret_cast<f16x4*>(&As[buf][aw0])           = vhi;                  \
    *reinterpret_cast<f16x4*>(&As[buf][aw0 + 2 * APL]) = vlo;                  \
  }

  // prologue: DMA B(0)->Bs[0], B(1)->Bs[1]; split A(0); prefetch raw A(1)
  GLD_LDS16(W1F + (size_t)tid * 8, &Bs[0][tid * 8]);
  GLD_LDS16(W1F + (size_t)(1024 + tid) * 8, &Bs[0][8192 + tid * 8]);
  GLD_LDS16(W1F + BSTEP + (size_t)tid * 8, &Bs[1][tid * 8]);
  GLD_LDS16(W1F + BSTEP + (size_t)(1024 + tid) * 8, &Bs[1][8192 + tid * 8]);
  float4 av = *reinterpret_cast<const float4*>(Aptr);
  SPLIT4(0, av)
  av = *reinterpret_cast<const float4*>(Aptr + 32);
  // in flight: DMA(0) x2 (wait), DMA(1) x2 + av x1 (3 younger) -> vmcnt(3)
  asm volatile("s_waitcnt vmcnt(3) lgkmcnt(0)" ::: "memory");
  __builtin_amdgcn_s_barrier();
  asm volatile("" ::: "memory");

  for (int s = 0; s < 32; ++s) {
    const int cur = s & 1;
    const int bcur = s % 3, bnxt = (s + 2) % 3;
    const f16* bsrc = W1F + (size_t)((s + 2) < 32 ? (s + 2) : 0) * BSTEP;

    // ============ phase 0 : kc0 ============
    {
      // (a) ds_read kc0 fragments
      const f16* ab = &As[cur][ar0];
      f16x4 h0 = *reinterpret_cast<const f16x4*>(ab);
      f16x4 h1 = *reinterpret_cast<const f16x4*>(ab + 4);
      f16x4 x0 = *reinterpret_cast<const f16x4*>(ab + 2 * APL);
      f16x4 x1 = *reinterpret_cast<const f16x4*>(ab + 2 * APL + 4);
      f16x8 ahi = __builtin_shufflevector(h0, h1, 0, 1, 2, 3, 4, 5, 6, 7);
      f16x8 axl = __builtin_shufflevector(x0, x1, 0, 1, 2, 3, 4, 5, 6, 7);
      const f16* bb0 = &Bs[bcur][br0];
      f16x8 wh0 = *reinterpret_cast<const f16x8*>(bb0);
      f16x8 wl0 = *reinterpret_cast<const f16x8*>(bb0 + 8192);
      f16x8 wh1 = *reinterpret_cast<const f16x8*>(bb0 + 512);
      f16x8 wl1 = *reinterpret_cast<const f16x8*>(bb0 + 512 + 8192);
      // (b) stage: DMA(s+2) first half + split tile s+1
      GLD_LDS16(bsrc + (size_t)tid * 8, &Bs[bnxt][tid * 8]);
      if (s < 31) SPLIT4(cur ^ 1, av)
      // (c) phase barrier + drain ds
      __builtin_amdgcn_s_barrier();
      asm volatile("s_waitcnt lgkmcnt(0)" ::: "memory");
      __builtin_amdgcn_sched_barrier(0);
      // (d) MFMA cluster kc0
      __builtin_amdgcn_s_setprio(1);
      MM3(accA[0], accB[0], ahi, axl, wh0, wl0)
      MM3(accA[1], accB[1], ahi, axl, wh1, wl1)
      __builtin_amdgcn_s_setprio(0);
      // (e) phase end barrier
      __builtin_amdgcn_s_barrier();
    }
    // ============ phase 1 : kc1 ============
    {
      // (a) ds_read kc1 fragments
      const f16* ab = &As[cur][APL + ar0];
      f16x4 h0 = *reinterpret_cast<const f16x4*>(ab);
      f16x4 h1 = *reinterpret_cast<const f16x4*>(ab + 4);
      f16x4 x0 = *reinterpret_cast<const f16x4*>(ab + 2 * APL);
      f16x4 x1 = *reinterpret_cast<const f16x4*>(ab + 2 * APL + 4);
      f16x8 ahi = __builtin_shufflevector(h0, h1, 0, 1, 2, 3, 4, 5, 6, 7);
      f16x8 axl = __builtin_shufflevector(x0, x1, 0, 1, 2, 3, 4, 5, 6, 7);
      const f16* bb1 = &Bs[bcur][4096 + br0];
      f16x8 wh0 = *reinterpret_cast<const f16x8*>(bb1);
      f16x8 wl0 = *reinterpret_cast<const f16x8*>(bb1 + 8192);
      f16x8 wh1 = *reinterpret_cast<const f16x8*>(bb1 + 512);
      f16x8 wl1 = *reinterpret_cast<const f16x8*>(bb1 + 512 + 8192);
      // (b) stage: DMA(s+2) second half + A raw prefetch (dummy-safe at tail)
      GLD_LDS16(bsrc + (size_t)(1024 + tid) * 8, &Bs[bnxt][8192 + tid * 8]);
      av = *reinterpret_cast<const float4*>(s < 30 ? Aptr + (s + 2) * 32 : Aptr);
      // (c) phase barrier + drain ds
      __builtin_amdgcn_s_barrier();
      asm volatile("s_waitcnt lgkmcnt(0)" ::: "memory");
      __builtin_amdgcn_sched_barrier(0);
      // (d) MFMA cluster kc1
      __builtin_amdgcn_s_setprio(1);
      MM3(accA[0], accB[0], ahi, axl, wh0, wl0)
      MM3(accA[1], accB[1], ahi, axl, wh1, wl1)
      __builtin_amdgcn_s_setprio(0);
      // (e) end-of-step: counted vmcnt (DMA(s+1) drained, DMA(s+2)+av stay
      //     in flight) + barrier
      asm volatile("s_waitcnt vmcnt(3)" ::: "memory");
      __builtin_amdgcn_s_barrier();
      asm volatile("" ::: "memory");
    }
  }

  __syncthreads();   // full drain (incl. tail dummy DMAs) before epilogue

  // finish stats: row owned by 8 threads (kq 0..7)
  rsum += __shfl_xor(rsum, 1); rsum += __shfl_xor(rsum, 2); rsum += __shfl_xor(rsum, 4);
  rsq  += __shfl_xor(rsq, 1);  rsq  += __shfl_xor(rsq, 2);  rsq  += __shfl_xor(rsq, 4);
  if ((tid & 7) == 0) {
    float mu  = rsum * (1.f / 1024.f);
    float var = rsq * (1.f / 1024.f) - mu * mu;
    smu[arow] = mu;
    srs[arow] = rsqrtf(var + 1e-5f);
  }
  __syncthreads();

  // epilogue: 32x32 C/D layout: col = lane&31, row = (reg&3)+8*(reg>>2)+4*(lane>>5)
  float s2[2], tb2[2], w2v[2];
  #pragma unroll
  for (int nf = 0; nf < 2; ++nf) {
    int col = cg * 64 + nf * 32 + c31;
    s2[nf] = S[col]; tb2[nf] = Tb[col]; w2v[nf] = W2[col];
  }
  #pragma unroll
  for (int reg = 0; reg < 16; ++reg) {
    const int row = rg * 32 + (reg & 3) + 8 * (reg >> 2) + 4 * kh;
    float mu = smu[row], rs = srs[row];
    float part = 0.f;
    #pragma unroll
    for (int nf = 0; nf < 2; ++nf) {
      float val = accA[nf][reg] + accB[nf][reg] * (1.f / 2048.f);
      float hpre = rs * val - rs * mu * s2[nf] + tb2[nf];
      float g = 0.5f * hpre * (1.f + erff(hpre * 0.70710678118654752f));
      part = fmaf(g, w2v[nf], part);
    }
    part += __shfl_xor(part, 1); part += __shfl_xor(part, 2);
    part += __shfl_xor(part, 4); part += __shfl_xor(part, 8);
    part += __shfl_xor(part, 16);
    if (c31 == 0) sred[row][cg] = part;
  }
  __syncthreads();
  if (tid < 128) {
    float sc = b2[0] + sred[tid][0] + sred[tid][1] + sred[tid][2] + sred[tid][3];
    scores_out[RM + tid] = sc;
  }
}

// ---------------- topk stage 1: 64 blocks, each sorts a 1024-score chunk
// (keys ascending = scores descending, idx-asc ties) and keeps top 512.
__global__ __launch_bounds__(512) void topk_stage1(
    const float* __restrict__ scores, u64* __restrict__ kout) {
  __shared__ u64 keys[1024];
  const int blk = blockIdx.x;
  const int batch = blk >> 3, chunk = blk & 7;
  const int t = threadIdx.x;
  #pragma unroll
  for (int j = 0; j < 2; ++j) {
    int i = t + j * 512;
    int gi = chunk * 1024 + i;                 // within-batch index
    unsigned u = __float_as_uint(scores[(size_t)batch * Lk + gi]);
    unsigned mono = (u & 0x80000000u) ? ~u : (u | 0x80000000u);
    keys[i] = ((u64)(~mono) << 32) | (unsigned)gi;
  }
  __syncthreads();
  for (int size = 2; size <= 1024; size <<= 1) {
    for (int stride = size >> 1; stride > 0; stride >>= 1) {
      int lo = ((t & ~(stride - 1)) << 1) | (t & (stride - 1));
      int hi = lo + stride;
      bool up = ((lo & size) == 0);
      u64 a = keys[lo], c = keys[hi];
      if ((a > c) == up) { keys[lo] = c; keys[hi] = a; }
      __syncthreads();
    }
  }
  kout[(size_t)blk * 512 + t] = keys[t];       // smallest 512 keys = top scores
}

// ---------------- topk stage 2: 8 blocks, tree-merge 8 sorted 512-lists.
__global__ __launch_bounds__(512) void topk_stage2(
    const u64* __restrict__ kin, int k,
    float* __restrict__ idx_f, int* __restrict__ idx_i) {
  __shared__ u64 kk[4096];
  __shared__ u64 tmp[2048];
  const int b = blockIdx.x, t = threadIdx.x;
  #pragma unroll
  for (int j = 0; j < 8; ++j) kk[t + j * 512] = kin[(size_t)b * 4096 + t + j * 512];
  __syncthreads();
  // level 0: kk (8 runs) -> tmp (4 runs)
  #pragma unroll
  for (int j = 0; j < 4; ++j) {
    u64 a = kk[j * 1024 + t];
    u64 c = kk[j * 1024 + 512 + (511 - t)];
    tmp[j * 512 + t] = a < c ? a : c;
  }
  __syncthreads();
  for (int stride = 256; stride > 0; stride >>= 1) {
    #pragma unroll
    for (int w = 0; w < 2; ++w) {
      int p = t + w * 512;                     // 1024 disjoint pairs
      int r = p >> 8, q = p & 255;
      int lo = r * 512 + (((q & ~(stride - 1)) << 1) | (q & (stride - 1)));
      u64 a = tmp[lo], c = tmp[lo + stride];
      if (a > c) { tmp[lo] = c; tmp[lo + stride] = a; }
    }
    __syncthreads();
  }
  // level 1: tmp (4 runs) -> kk (2 runs)
  #pragma unroll
  for (int j = 0; j < 2; ++j) {
    u64 a = tmp[j * 1024 + t];
    u64 c = tmp[j * 1024 + 512 + (511 - t)];
    kk[j * 512 + t] = a < c ? a : c;
  }
  __syncthreads();
  for (int stride = 256; stride > 0; stride >>= 1) {
    int r = t >> 8, q = t & 255;               // 512 pairs over 2 runs
    int lo = r * 512 + (((q & ~(stride - 1)) << 1) | (q & (stride - 1)));
    u64 a = kk[lo], c = kk[lo + stride];
    if (a > c) { kk[lo] = c; kk[lo + stride] = a; }
    __syncthreads();
  }
  // level 2: kk (2 runs) -> tmp[0..512)
  {
    u64 a = kk[t];
    u64 c = kk[512 + (511 - t)];
    tmp[t] = a < c ? a : c;
  }
  __syncthreads();
  for (int stride = 256; stride > 0; stride >>= 1) {
    if (t < 256) {
      int lo = ((t & ~(stride - 1)) << 1) | (t & (stride - 1));
      u64 a = tmp[lo], c = tmp[lo + stride];
      if (a > c) { tmp[lo] = c; tmp[lo + stride] = a; }
    }
    __syncthreads();
  }
  if (t < k) {
    int id = (int)(tmp[t] & 0xFFFFFFFFu);
    idx_f[(size_t)b * k + t] = (float)id;
    idx_i[(size_t)b * k + t] = id;
  }
}

// ---------------- gather: one block per selected row, 4 KB float4 copy
__global__ __launch_bounds__(256) void gather_kernel(
    const float* __restrict__ F, const int* __restrict__ idx,
    float* __restrict__ out, int k) {
  int row = blockIdx.x;          // 0 .. 8*k-1
  int b = row / k;
  int id = idx[row];
  const float4* src = reinterpret_cast<const float4*>(F + ((size_t)b * Lk + id) * Dk);
  float4* dst = reinterpret_cast<float4*>(out + (size_t)row * Dk);
  dst[threadIdx.x] = src[threadIdx.x];
}

extern "C" void kernel_launch(void* const* d_in, const int* in_sizes, int n_in,
                              void* d_out, int out_size, void* d_ws, size_t ws_size,
                              hipStream_t stream) {
  const float* F     = (const float*)d_in[0];
  const float* gamma = (const float*)d_in[1];
  const float* beta  = (const float*)d_in[2];
  const float* W1    = (const float*)d_in[3];
  const float* b1    = (const float*)d_in[4];
  const float* W2    = (const float*)d_in[5];
  const float* b2    = (const float*)d_in[6];
  // k lives on device; derive on host from out_size = 8*k*1024 + 8*8192 + 8*k
  int k = (out_size - Bk * Lk) / (Bk * Dk + Bk);   // = 512

  float* out_sel = (float*)d_out;                       // [8, k, 1024]
  float* out_sc  = out_sel + (size_t)Bk * k * Dk;       // [8, 8192]
  float* out_idx = out_sc + (size_t)Bk * Lk;            // [8, k] as float

  // ws: W1F f16[524288] (1MB) | kout u64[32768] (256KB) | Spart f32[16384] |
  //     Tpart f32[16384] | S f32[256] | Tb f32[256] | idxi i32[8*k]
  f16*   W1F   = (f16*)d_ws;
  u64*   kout  = (u64*)((char*)d_ws + (1 << 20));
  float* Spart = (float*)((char*)kout + 262144);
  float* Tpart = Spart + 16384;
  float* Sp    = Tpart + 16384;
  float* Tbp   = Sp + Hk;
  int*   idxi  = (int*)(Tbp + Hk);

  hipLaunchKernelGGL(prep_split,   dim3(64),         dim3(1024), 0, stream,
                     W1, gamma, beta, W1F, Spart, Tpart);
  hipLaunchKernelGGL(prep_combine, dim3(1),          dim3(Hk),   0, stream,
                     Spart, Tpart, b1, Sp, Tbp);
  hipLaunchKernelGGL(scores_mfma,  dim3(MTOT / 128), dim3(1024), 0, stream,
                     F, W1F, Sp, Tbp, W2, b2, out_sc);
  hipLaunchKernelGGL(topk_stage1,  dim3(64),         dim3(512),  0, stream,
                     out_sc, kout);
  hipLaunchKernelGGL(topk_stage2,  dim3(Bk),         dim3(512),  0, stream,
                     kout, k, out_idx, idxi);
  hipLaunchKernelGGL(gather_kernel, dim3(Bk * k),    dim3(256),  0, stream,
                     F, idxi, out_sel, k);
}

// Round 16
// 156.337 us; speedup vs baseline: 1.0814x; 1.0505x over previous
//
#include <hip/hip_runtime.h>
#include <math.h>

#define Dk 1024
#define Hk 256
#define Lk 8192
#define Bk 8
#define MTOT (Bk*Lk)   // 65536 rows

typedef _Float16 f16;
typedef __attribute__((ext_vector_type(8))) _Float16 f16x8;
typedef __attribute__((ext_vector_type(4))) float f32x4;
typedef unsigned long long u64;

#define AKG 1048            // padded kg stride (128 rows * 8 + 24)
#define ASP (8*AKG)         // split-plane stride
#define ABUF (2*ASP)        // elems per A LDS buffer (hi+lo)

// ---------------- prep_split: W1 -> gamma-folded fp16 2-way split (hi, lo*2048)
// in MFMA-fragment order, PLUS partials for S = gamma@W1, T = beta@W1.
// Layout: W1F[ks(16)][sp(2)][nf(16)][kg(8)][n(16)][k(8)], d=ks*64+kg*8+k, h=nf*16+n.
__global__ __launch_bounds__(1024) void prep_split(
    const float* __restrict__ W1, const float* __restrict__ gamma,
    const float* __restrict__ beta, f16* __restrict__ W1F,
    float* __restrict__ Spart, float* __restrict__ Tpart) {
  __shared__ float ps[1024], pt[1024];
  const int b = blockIdx.x, t = threadIdx.x;
  float sa = 0.f, ta = 0.f;
  #pragma unroll
  for (int j = 0; j < 4; ++j) {
    int idx = j * 65536 + b * 1024 + t;
    int d = idx >> 8, h = idx & 255;
    float w = W1[idx];
    float g = gamma[d];
    sa = fmaf(g, w, sa);
    ta = fmaf(beta[d], w, ta);
    float wg = g * w;                       // gamma folded into W1
    f16 whi = (f16)wg;
    f16 wlp = (f16)((wg - (float)whi) * 2048.f);   // scaled lo: stays fp16-normal
    int ks = d >> 6, kg = (d >> 3) & 7, kk = d & 7;
    int nf = h >> 4, nn = h & 15;
    size_t base = ((((size_t)ks * 2) * 16 + nf) * 8 + kg) * 128 + nn * 8 + kk;
    W1F[base] = whi;
    W1F[base + 16384] = wlp;                // sp stride = 16*8*128
  }
  ps[t] = sa; pt[t] = ta;
  __syncthreads();
  if (t < 256) {
    Spart[b * 256 + t] = ps[t] + ps[t + 256] + ps[t + 512] + ps[t + 768];
    Tpart[b * 256 + t] = pt[t] + pt[t + 256] + pt[t + 512] + pt[t + 768];
  }
}

__global__ __launch_bounds__(256) void prep_combine(
    const float* __restrict__ Spart, const float* __restrict__ Tpart,
    const float* __restrict__ b1, float* __restrict__ S, float* __restrict__ Tb) {
  int j = threadIdx.x;
  float s = 0.f, t = 0.f;
  for (int b = 0; b < 64; ++b) { s += Spart[b * 256 + j]; t += Tpart[b * 256 + j]; }
  S[j] = s;
  Tb[j] = t + b1[j];
}

// 3-product split-fp16 triple: accA += ah*wh; accB += ah*wl + ax*wh
#define MM3(aA, aB, ah, ax, wh, wl)                                            \
  aA = __builtin_amdgcn_mfma_f32_16x16x32_f16(ah, wh, aA, 0, 0, 0);            \
  aB = __builtin_amdgcn_mfma_f32_16x16x32_f16(ah, wl, aB, 0, 0, 0);            \
  aB = __builtin_amdgcn_mfma_f32_16x16x32_f16(ax, wh, aB, 0, 0, 0);

// ---------------- scores: fused LN + Linear(1024->256) + GELU + Linear(256->1)
// fp16 2-way-split MFMA, 3 products, dual acc. BM=128, BN=256, BK=64, 16 steps.
// 1024 thr = 16 waves, wave tile 128x16 (8 mf x 1 nf): each wave owns ONE
// 16-col slice => per-step B loads are the UNIQUE 64KB (no duplication).
// acc = 32+32 AGPR, B-live = 8 VGPR, VGPR 64 -> 16 waves/CU.
// EMPIRICAL BEST (R12 = 157.0 us total): R13 (DMA+conflict-fix), R14 (counted
// vmcnt + triple buffer), R15 (phase-split + setprio) all measured 162-169 us
// with MfmaUtil pinned 26-28% -- the wall is a latency-chain plateau, not any
// single pipe; reverting to the measured optimum.
__global__ __launch_bounds__(1024) void scores_mfma(
    const float* __restrict__ F, const f16* __restrict__ W1F,
    const float* __restrict__ S, const float* __restrict__ Tb,
    const float* __restrict__ W2, const float* __restrict__ b2,
    float* __restrict__ scores_out) {
  __shared__ __align__(16) f16 As[2][ABUF];    // 2 x 33.5KB: [sp][kg(8)][row(128)][k8]
  __shared__ float smu[128], srs[128];
  __shared__ float sred[128][16];

  const int tid = threadIdx.x;
  const int RM = blockIdx.x * 128;
  const int wid = tid >> 6, lane = tid & 63;   // wid 0..15 = 16-col slice owner
  const int lg = lane >> 4, l15 = lane & 15;

  // A staging: thread -> (row 0..127, one k8-group of the 64-wide K step)
  const int arow = tid >> 3, kg = tid & 7;
  const float* Aptr = F + (size_t)(RM + arow) * Dk + kg * 8;

  const int aoff = lg * AKG + l15 * 8;          // A frag base: +mf*128, +4*AKG kw1, +ASP lo
  const int boff = wid * 1024 + lg * 128 + l15 * 8;  // B frag base: +512 kw1, +16384 lo

  f32x4 accA[8], accB[8];
  #pragma unroll
  for (int i = 0; i < 8; ++i) {
    accA[i] = (f32x4){0.f, 0.f, 0.f, 0.f};
    accB[i] = (f32x4){0.f, 0.f, 0.f, 0.f};
  }

  float rsum = 0.f, rsq = 0.f;

  // stats + fp16 2-way split of 8 raw elems -> two b128 LDS writes
#define SPLIT_STORE(buf, av0, av1)                                             \
  {                                                                            \
    f16x8 vhi, vlo;                                                            \
    _Pragma("unroll")                                                          \
    for (int e = 0; e < 8; ++e) {                                              \
      float x = (e < 4) ? ((e == 0) ? av0.x : (e == 1) ? av0.y                 \
                           : (e == 2) ? av0.z : av0.w)                         \
                        : ((e == 4) ? av1.x : (e == 5) ? av1.y                 \
                           : (e == 6) ? av1.z : av1.w);                        \
      rsum += x; rsq = fmaf(x, x, rsq);                                        \
      f16 hi = (f16)x;                                                         \
      vhi[e] = hi;                                                             \
      vlo[e] = (f16)((x - (float)hi) * 2048.f);                                \
    }                                                                          \
    *reinterpret_cast<f16x8*>(&As[buf][kg * AKG + arow * 8]) = vhi;            \
    *reinterpret_cast<f16x8*>(&As[buf][ASP + kg * AKG + arow * 8]) = vlo;      \
  }

  // prologue: stage tile 0, prefetch raw tile 1
  float4 av0 = *reinterpret_cast<const float4*>(Aptr);
  float4 av1 = *reinterpret_cast<const float4*>(Aptr + 4);
  SPLIT_STORE(0, av0, av1)
  av0 = *reinterpret_cast<const float4*>(Aptr + 64);
  av1 = *reinterpret_cast<const float4*>(Aptr + 68);
  __syncthreads();

  for (int s = 0; s < 16; ++s) {
    const int cur = s & 1;
    const f16* bs = W1F + (size_t)s * 32768 + boff;
    // issue ALL B loads for this step first (8 regs live; latency hidden by split)
    f16x8 wh0 = *reinterpret_cast<const f16x8*>(bs);             // kw0 hi
    f16x8 wl0 = *reinterpret_cast<const f16x8*>(bs + 16384);     // kw0 lo
    f16x8 wh1 = *reinterpret_cast<const f16x8*>(bs + 512);       // kw1 hi
    f16x8 wl1 = *reinterpret_cast<const f16x8*>(bs + 512 + 16384);
    // split tile s+1 (pure VALU + LDS writes; overlaps the loads above)
    if (s < 15) {
      SPLIT_STORE(cur ^ 1, av0, av1)
      if (s < 14) {
        av0 = *reinterpret_cast<const float4*>(Aptr + (s + 2) * 64);
        av1 = *reinterpret_cast<const float4*>(Aptr + (s + 2) * 64 + 4);
      }
    }
    // kw0 MFMAs (A frags from LDS)
    #pragma unroll
    for (int mf = 0; mf < 8; ++mf) {
      const int ao = aoff + mf * 128;
      f16x8 ahi = *reinterpret_cast<const f16x8*>(&As[cur][ao]);
      f16x8 axl = *reinterpret_cast<const f16x8*>(&As[cur][ASP + ao]);
      MM3(accA[mf], accB[mf], ahi, axl, wh0, wl0)
    }
    // kw1 MFMAs
    #pragma unroll
    for (int mf = 0; mf < 8; ++mf) {
      const int ao = aoff + 4 * AKG + mf * 128;
      f16x8 ahi = *reinterpret_cast<const f16x8*>(&As[cur][ao]);
      f16x8 axl = *reinterpret_cast<const f16x8*>(&As[cur][ASP + ao]);
      MM3(accA[mf], accB[mf], ahi, axl, wh1, wl1)
    }
    __syncthreads();  // one barrier/step
  }

  // finish stats: row owned by 8 threads (kg 0..7)
  rsum += __shfl_xor(rsum, 1); rsum += __shfl_xor(rsum, 2); rsum += __shfl_xor(rsum, 4);
  rsq  += __shfl_xor(rsq, 1);  rsq  += __shfl_xor(rsq, 2);  rsq  += __shfl_xor(rsq, 4);
  if ((tid & 7) == 0) {
    float mu  = rsum * (1.f / 1024.f);
    float var = rsq * (1.f / 1024.f) - mu * mu;
    smu[arow] = mu;
    srs[arow] = rsqrtf(var + 1e-5f);
  }
  __syncthreads();

  // epilogue: C/D col=l15, row=lg*4+reg (within mf*16 frag). val = accA +
  // accB/2048; LN affine + GELU(exact) + W2 dot; 16-lane reduce; cross-wave
  // via sred[row][wid] (fixed order => deterministic).
  const int col = wid * 16 + l15;
  const float s2 = S[col], tb2 = Tb[col], w2v = W2[col];
  #pragma unroll
  for (int mf = 0; mf < 8; ++mf) {
    const int rbase = mf * 16 + lg * 4;
    #pragma unroll
    for (int reg = 0; reg < 4; ++reg) {
      const int row = rbase + reg;
      float mu = smu[row], rs = srs[row];
      float val = accA[mf][reg] + accB[mf][reg] * (1.f / 2048.f);
      float hpre = rs * val - rs * mu * s2 + tb2;
      float g = 0.5f * hpre * (1.f + erff(hpre * 0.70710678118654752f));
      float part = g * w2v;
      part += __shfl_xor(part, 1); part += __shfl_xor(part, 2);
      part += __shfl_xor(part, 4); part += __shfl_xor(part, 8);
      if (l15 == 0) sred[row][wid] = part;
    }
  }
  __syncthreads();
  if (tid < 128) {
    float sc = b2[0];
    #pragma unroll
    for (int w = 0; w < 16; ++w) sc += sred[tid][w];
    scores_out[RM + tid] = sc;
  }
}

// ---------------- topk stage 1: 64 blocks, each sorts a 1024-score chunk
// (keys ascending = scores descending, idx-asc ties) and keeps top 512.
__global__ __launch_bounds__(512) void topk_stage1(
    const float* __restrict__ scores, u64* __restrict__ kout) {
  __shared__ u64 keys[1024];
  const int blk = blockIdx.x;
  const int batch = blk >> 3, chunk = blk & 7;
  const int t = threadIdx.x;
  #pragma unroll
  for (int j = 0; j < 2; ++j) {
    int i = t + j * 512;
    int gi = chunk * 1024 + i;                 // within-batch index
    unsigned u = __float_as_uint(scores[(size_t)batch * Lk + gi]);
    unsigned mono = (u & 0x80000000u) ? ~u : (u | 0x80000000u);
    keys[i] = ((u64)(~mono) << 32) | (unsigned)gi;
  }
  __syncthreads();
  for (int size = 2; size <= 1024; size <<= 1) {
    for (int stride = size >> 1; stride > 0; stride >>= 1) {
      int lo = ((t & ~(stride - 1)) << 1) | (t & (stride - 1));
      int hi = lo + stride;
      bool up = ((lo & size) == 0);
      u64 a = keys[lo], c = keys[hi];
      if ((a > c) == up) { keys[lo] = c; keys[hi] = a; }
      __syncthreads();
    }
  }
  kout[(size_t)blk * 512 + t] = keys[t];       // smallest 512 keys = top scores
}

// ---------------- topk stage 2: 8 blocks, tree-merge 8 sorted 512-lists.
__global__ __launch_bounds__(512) void topk_stage2(
    const u64* __restrict__ kin, int k,
    float* __restrict__ idx_f, int* __restrict__ idx_i) {
  __shared__ u64 kk[4096];
  __shared__ u64 tmp[2048];
  const int b = blockIdx.x, t = threadIdx.x;
  #pragma unroll
  for (int j = 0; j < 8; ++j) kk[t + j * 512] = kin[(size_t)b * 4096 + t + j * 512];
  __syncthreads();
  // level 0: kk (8 runs) -> tmp (4 runs)
  #pragma unroll
  for (int j = 0; j < 4; ++j) {
    u64 a = kk[j * 1024 + t];
    u64 c = kk[j * 1024 + 512 + (511 - t)];
    tmp[j * 512 + t] = a < c ? a : c;
  }
  __syncthreads();
  for (int stride = 256; stride > 0; stride >>= 1) {
    #pragma unroll
    for (int w = 0; w < 2; ++w) {
      int p = t + w * 512;                     // 1024 disjoint pairs
      int r = p >> 8, q = p & 255;
      int lo = r * 512 + (((q & ~(stride - 1)) << 1) | (q & (stride - 1)));
      u64 a = tmp[lo], c = tmp[lo + stride];
      if (a > c) { tmp[lo] = c; tmp[lo + stride] = a; }
    }
    __syncthreads();
  }
  // level 1: tmp (4 runs) -> kk (2 runs)
  #pragma unroll
  for (int j = 0; j < 2; ++j) {
    u64 a = tmp[j * 1024 + t];
    u64 c = tmp[j * 1024 + 512 + (511 - t)];
    kk[j * 512 + t] = a < c ? a : c;
  }
  __syncthreads();
  for (int stride = 256; stride > 0; stride >>= 1) {
    int r = t >> 8, q = t & 255;               // 512 pairs over 2 runs
    int lo = r * 512 + (((q & ~(stride - 1)) << 1) | (q & (stride - 1)));
    u64 a = kk[lo], c = kk[lo + stride];
    if (a > c) { kk[lo] = c; kk[lo + stride] = a; }
    __syncthreads();
  }
  // level 2: kk (2 runs) -> tmp[0..512)
  {
    u64 a = kk[t];
    u64 c = kk[512 + (511 - t)];
    tmp[t] = a < c ? a : c;
  }
  __syncthreads();
  for (int stride = 256; stride > 0; stride >>= 1) {
    if (t < 256) {
      int lo = ((t & ~(stride - 1)) << 1) | (t & (stride - 1));
      u64 a = tmp[lo], c = tmp[lo + stride];
      if (a > c) { tmp[lo] = c; tmp[lo + stride] = a; }
    }
    __syncthreads();
  }
  if (t < k) {
    int id = (int)(tmp[t] & 0xFFFFFFFFu);
    idx_f[(size_t)b * k + t] = (float)id;
    idx_i[(size_t)b * k + t] = id;
  }
}

// ---------------- gather: one block per selected row, 4 KB float4 copy
__global__ __launch_bounds__(256) void gather_kernel(
    const float* __restrict__ F, const int* __restrict__ idx,
    float* __restrict__ out, int k) {
  int row = blockIdx.x;          // 0 .. 8*k-1
  int b = row / k;
  int id = idx[row];
  const float4* src = reinterpret_cast<const float4*>(F + ((size_t)b * Lk + id) * Dk);
  float4* dst = reinterpret_cast<float4*>(out + (size_t)row * Dk);
  dst[threadIdx.x] = src[threadIdx.x];
}

extern "C" void kernel_launch(void* const* d_in, const int* in_sizes, int n_in,
                              void* d_out, int out_size, void* d_ws, size_t ws_size,
                              hipStream_t stream) {
  const float* F     = (const float*)d_in[0];
  const float* gamma = (const float*)d_in[1];
  const float* beta  = (const float*)d_in[2];
  const float* W1    = (const float*)d_in[3];
  const float* b1    = (const float*)d_in[4];
  const float* W2    = (const float*)d_in[5];
  const float* b2    = (const float*)d_in[6];
  // k lives on device; derive on host from out_size = 8*k*1024 + 8*8192 + 8*k
  int k = (out_size - Bk * Lk) / (Bk * Dk + Bk);   // = 512

  float* out_sel = (float*)d_out;                       // [8, k, 1024]
  float* out_sc  = out_sel + (size_t)Bk * k * Dk;       // [8, 8192]
  float* out_idx = out_sc + (size_t)Bk * Lk;            // [8, k] as float

  // ws: W1F f16[524288] (1MB) | kout u64[32768] (256KB) | Spart f32[16384] |
  //     Tpart f32[16384] | S f32[256] | Tb f32[256] | idxi i32[8*k]
  f16*   W1F   = (f16*)d_ws;
  u64*   kout  = (u64*)((char*)d_ws + (1 << 20));
  float* Spart = (float*)((char*)kout + 262144);
  float* Tpart = Spart + 16384;
  float* Sp    = Tpart + 16384;
  float* Tbp   = Sp + Hk;
  int*   idxi  = (int*)(Tbp + Hk);

  hipLaunchKernelGGL(prep_split,   dim3(64),         dim3(1024), 0, stream,
                     W1, gamma, beta, W1F, Spart, Tpart);
  hipLaunchKernelGGL(prep_combine, dim3(1),          dim3(Hk),   0, stream,
                     Spart, Tpart, b1, Sp, Tbp);
  hipLaunchKernelGGL(scores_mfma,  dim3(MTOT / 128), dim3(1024), 0, stream,
                     F, W1F, Sp, Tbp, W2, b2, out_sc);
  hipLaunchKernelGGL(topk_stage1,  dim3(64),         dim3(512),  0, stream,
                     out_sc, kout);
  hipLaunchKernelGGL(topk_stage2,  dim3(Bk),         dim3(512),  0, stream,
                     kout, k, out_idx, idxi);
  hipLaunchKernelGGL(gather_kernel, dim3(Bk * k),    dim3(256),  0, stream,
                     F, idxi, out_sel, k);
}